// Round 1
// baseline (298.955 us; speedup 1.0000x reference)
//
#include <hip/hip_runtime.h>

#define T_STEPS 65536
#define NZ 64
#define NH1 128
#define NH2 64
#define NEDGE 512
#define NCHUNK 2048
#define CHUNK_L 32   // T_STEPS / NCHUNK
#define NSUPER 32
#define SUP_L 64     // NCHUNK / NSUPER

// ws layout (bytes)
#define ADJ_OFF        0          // 64 * u64                    = 512
#define BASE1_OFF      512        // 128 * f64                   = 1024
#define W1T_OFF        1536       // 128 * f64                   = 1024
#define CHUNKG_OFF     4096       // NCHUNK*64 u8                = 131072
#define SUPERS_OFF     135168     // NSUPER*64 u8                = 2048
#define SUPSTATE_OFF   137216     // NSUPER * i32                = 128
#define CHUNKSTATE_OFF 137344     // NCHUNK * i32                = 8192
#define LG64_OFF       145536     // T*64 f64                    = 33554432
#define WS_NEED_F64    (LG64_OFF + (size_t)T_STEPS * NZ * 8)

// ---------------------------------------------------------------------------
// Kernel 1: adjacency bitmasks + base1/w1t precompute (single block)
// ---------------------------------------------------------------------------
__global__ void prep_kernel(const float* __restrict__ pa,
                            const int* __restrict__ edges,
                            const float* __restrict__ W1,
                            const float* __restrict__ b1,
                            unsigned char* ws) {
  unsigned long long* adj = (unsigned long long*)(ws + ADJ_OFF);
  double* base1 = (double*)(ws + BASE1_OFF);
  double* w1t   = (double*)(ws + W1T_OFF);
  int tid = threadIdx.x;
  if (tid < NZ) adj[tid] = 0ull;
  __syncthreads();
  if (tid < NEDGE) {
    int e0 = edges[tid];
    int e1 = edges[NEDGE + tid];
    atomicOr(&adj[e0], 1ull << e1);
    atomicOr(&adj[e1], 1ull << e0);
  }
  if (tid < NZ) atomicOr(&adj[tid], 1ull << tid);  // self loops
  if (tid < NH1) {
    double acc = (double)b1[tid];
    for (int d = 0; d < 64; ++d)
      acc += (double)pa[d] * (double)W1[d * NH1 + tid];
    base1[tid] = acc;
    w1t[tid] = (double)W1[64 * NH1 + tid];
  }
}

// ---------------------------------------------------------------------------
// Kernel 2: batched MLP -> logits (f32 to d_out, f64 to ws if available)
// one wave per 32 timesteps; weights staged in LDS; f64 accumulation
// ---------------------------------------------------------------------------
__global__ __launch_bounds__(256) void mlp_kernel(
    const float* __restrict__ times,
    const float* __restrict__ W2, const float* __restrict__ b2,
    const float* __restrict__ W3, const float* __restrict__ b3,
    const unsigned char* __restrict__ ws_ro,
    float* __restrict__ out, double* lg64) {
  __shared__ float W2s[NH1 * NH2];
  __shared__ float W3s[NH2 * NZ];
  __shared__ float b2s[NH2], b3s[NZ];
  __shared__ double base1s[NH1], w1ts[NH1];
  __shared__ double h1buf[4][NH1];
  __shared__ double h2buf[4][NH2];

  const double* base1 = (const double*)(ws_ro + BASE1_OFF);
  const double* w1t   = (const double*)(ws_ro + W1T_OFF);
  int tid = threadIdx.x;
  for (int i = tid; i < NH1 * NH2; i += 256) W2s[i] = W2[i];
  for (int i = tid; i < NH2 * NZ; i += 256) W3s[i] = W3[i];
  if (tid < NH2) b2s[tid] = b2[tid];
  if (tid < NZ)  b3s[tid] = b3[tid];
  if (tid < NH1) { base1s[tid] = base1[tid]; w1ts[tid] = w1t[tid]; }
  __syncthreads();

  int lane = tid & 63, wv = tid >> 6;
  int wid = blockIdx.x * 4 + wv;
  int t0 = wid * CHUNK_L;
  for (int i = 0; i < CHUNK_L; ++i) {
    int t = t0 + i;
    double tv = (double)times[t];
    double a0 = base1s[lane] + tv * w1ts[lane];
    double a1 = base1s[lane + 64] + tv * w1ts[lane + 64];
    h1buf[wv][lane]      = a0 > 0.0 ? a0 : 0.0;
    h1buf[wv][lane + 64] = a1 > 0.0 ? a1 : 0.0;
    __syncthreads();
    double acc = (double)b2s[lane];
    #pragma unroll 8
    for (int h = 0; h < NH1; ++h)
      acc += h1buf[wv][h] * (double)W2s[h * NH2 + lane];
    h2buf[wv][lane] = acc > 0.0 ? acc : 0.0;
    __syncthreads();
    double lg = (double)b3s[lane];
    #pragma unroll 8
    for (int j = 0; j < NH2; ++j)
      lg += h2buf[wv][j] * (double)W3s[j * NZ + lane];
    size_t base = (size_t)t * NZ + lane;
    out[base] = (float)lg;
    if (lg64) lg64[base] = lg;
  }
}

// ---------------------------------------------------------------------------
// Kernel 3: per-chunk composed transition tables (one wave per chunk)
// F_t[z] = argmax_j(logits_t[j] - 1 + A[z][j]); compose over 32 steps
// ---------------------------------------------------------------------------
__global__ __launch_bounds__(256) void chunk_tables_kernel(
    const float* __restrict__ lg32, const double* __restrict__ lg64,
    const unsigned char* __restrict__ ws_ro, unsigned char* __restrict__ chunkG) {
  const unsigned long long* adj = (const unsigned long long*)(ws_ro + ADJ_OFF);
  int lane = threadIdx.x & 63, wv = threadIdx.x >> 6;
  int c = blockIdx.x * 4 + wv;
  unsigned long long mask = adj[lane];  // lane z's neighbor mask
  int cur = lane;                       // composed table entry for z=lane
  int t0 = c * CHUNK_L;
  for (int i = 0; i < CHUNK_L; ++i) {
    size_t base = (size_t)(t0 + i) * NZ;
    double lg = lg64 ? lg64[base + lane] : (double)lg32[base + lane];
    double bestv = -1e300;
    int bestj = 0;
    for (int j = 0; j < NZ; ++j) {
      double vj = __shfl(lg, j, 64);
      double val = vj + (((mask >> j) & 1ull) ? 0.0 : -1.0);
      if (val > bestv) { bestv = val; bestj = j; }  // strict > keeps first idx
    }
    // compose: new_cur[z] = F_t[cur[z]]
    cur = __shfl(bestj, cur, 64);
  }
  chunkG[(size_t)c * 64 + lane] = (unsigned char)cur;
}

// ---------------------------------------------------------------------------
// Kernel 4: compose 64 chunk tables into each super table (32 waves)
// ---------------------------------------------------------------------------
__global__ void super_compose_kernel(const unsigned char* __restrict__ chunkG,
                                     unsigned char* __restrict__ superS) {
  int lane = threadIdx.x & 63, wv = threadIdx.x >> 6;
  int k = blockIdx.x * 4 + wv;
  int cur = lane;
  for (int c = k * SUP_L; c < (k + 1) * SUP_L; ++c) {
    int g = chunkG[(size_t)c * 64 + lane];
    cur = __shfl(g, cur, 64);
  }
  superS[(size_t)k * 64 + lane] = (unsigned char)cur;
}

// ---------------------------------------------------------------------------
// Kernel 5: sequential walk over 32 super tables (1 wave)
// ---------------------------------------------------------------------------
__global__ void super_walk_kernel(const unsigned char* __restrict__ superS,
                                  int* __restrict__ supState) {
  int lane = threadIdx.x;
  int s = 0;
  if (lane == 0) supState[0] = 0;
  for (int k = 0; k < NSUPER; ++k) {
    int v = superS[k * 64 + lane];
    s = __shfl(v, s, 64);  // s is uniform; stays uniform
    if (lane == 0 && k + 1 < NSUPER) supState[k + 1] = s;
  }
}

// ---------------------------------------------------------------------------
// Kernel 6: per-chunk start states within each super (32 waves)
// ---------------------------------------------------------------------------
__global__ void chunk_states_kernel(const unsigned char* __restrict__ chunkG,
                                    const int* __restrict__ supState,
                                    int* __restrict__ chunkState) {
  int lane = threadIdx.x & 63, wv = threadIdx.x >> 6;
  int k = blockIdx.x * 4 + wv;
  int s = supState[k];
  for (int c = k * SUP_L; c < (k + 1) * SUP_L; ++c) {
    if (lane == 0) chunkState[c] = s;
    int g = chunkG[(size_t)c * 64 + lane];
    s = __shfl(g, s, 64);
  }
}

// ---------------------------------------------------------------------------
// Kernel 7: finalize — roll each chunk forward from its start state,
// write out = logits - 1 + A[z_t] (in place over f32 logits in d_out)
// ---------------------------------------------------------------------------
__global__ __launch_bounds__(256) void finalize_kernel(
    const double* __restrict__ lg64, const unsigned char* __restrict__ ws_ro,
    const int* __restrict__ chunkState, float* __restrict__ out) {
  const unsigned long long* adj = (const unsigned long long*)(ws_ro + ADJ_OFF);
  int lane = threadIdx.x & 63, wv = threadIdx.x >> 6;
  int c = blockIdx.x * 4 + wv;
  int s = chunkState[c];
  int t0 = c * CHUNK_L;
  for (int i = 0; i < CHUNK_L; ++i) {
    size_t base = (size_t)(t0 + i) * NZ;
    float lgf = out[base + lane];
    double lg = lg64 ? lg64[base + lane] : (double)lgf;
    unsigned long long mask = adj[s];  // s uniform per wave
    int bit = (int)((mask >> lane) & 1ull);
    out[base + lane] = lgf - 1.0f + (float)bit;
    // transition: argmax over constrained values (f64, first-index ties)
    double v = lg + (bit ? 0.0 : -1.0);
    int idx = lane;
    #pragma unroll
    for (int off = 1; off < 64; off <<= 1) {
      double ov = __shfl_xor(v, off, 64);
      int oi = __shfl_xor(idx, off, 64);
      if (ov > v || (ov == v && oi < idx)) { v = ov; idx = oi; }
    }
    s = idx;  // uniform across lanes
  }
}

// ---------------------------------------------------------------------------
extern "C" void kernel_launch(void* const* d_in, const int* in_sizes, int n_in,
                              void* d_out, int out_size, void* d_ws, size_t ws_size,
                              hipStream_t stream) {
  const float* pa    = (const float*)d_in[0];
  const float* times = (const float*)d_in[1];
  // d_in[2] zone_features: unused by the reference
  const int*   edges = (const int*)d_in[3];
  const float* W1    = (const float*)d_in[4];
  const float* b1    = (const float*)d_in[5];
  const float* W2    = (const float*)d_in[6];
  const float* b2    = (const float*)d_in[7];
  const float* W3    = (const float*)d_in[8];
  const float* b3    = (const float*)d_in[9];

  unsigned char* ws = (unsigned char*)d_ws;
  float* out = (float*)d_out;
  double* lg64 = (ws_size >= WS_NEED_F64) ? (double*)(ws + LG64_OFF) : nullptr;

  hipLaunchKernelGGL(prep_kernel, dim3(1), dim3(512), 0, stream, pa, edges, W1, b1, ws);
  hipLaunchKernelGGL(mlp_kernel, dim3(NCHUNK / 4), dim3(256), 0, stream,
                     times, W2, b2, W3, b3, ws, out, lg64);
  hipLaunchKernelGGL(chunk_tables_kernel, dim3(NCHUNK / 4), dim3(256), 0, stream,
                     out, lg64, ws, ws + CHUNKG_OFF);
  hipLaunchKernelGGL(super_compose_kernel, dim3(NSUPER / 4), dim3(256), 0, stream,
                     ws + CHUNKG_OFF, ws + SUPERS_OFF);
  hipLaunchKernelGGL(super_walk_kernel, dim3(1), dim3(64), 0, stream,
                     ws + SUPERS_OFF, (int*)(ws + SUPSTATE_OFF));
  hipLaunchKernelGGL(chunk_states_kernel, dim3(NSUPER / 4), dim3(256), 0, stream,
                     ws + CHUNKG_OFF, (const int*)(ws + SUPSTATE_OFF),
                     (int*)(ws + CHUNKSTATE_OFF));
  hipLaunchKernelGGL(finalize_kernel, dim3(NCHUNK / 4), dim3(256), 0, stream,
                     lg64, ws, (const int*)(ws + CHUNKSTATE_OFF), out);
}

// Round 2
// 197.989 us; speedup vs baseline: 1.5100x; 1.5100x over previous
//
#include <hip/hip_runtime.h>

#define T_STEPS 65536
#define NZ 64
#define NH1 128
#define NH2 64
#define NEDGE 512
#define NCHUNK 8192
#define CL 8            // timesteps per chunk (T_STEPS / NCHUNK)
#define NSUPER 128
#define SUP_L 64        // chunks per super (NCHUNK / NSUPER)

// ---- ws layout (bytes). Total = 40960 + 32MB = 33,595,392 (< round-1 floor)
#define ADJ_OFF        0          // 64 * u64
#define BASE1_OFF      512        // 128 * f64
#define W1T_OFF        1536       // 128 * f64
#define NBRT_OFF       2560       // 64*64 u8, transposed [k][z]
#define MAXDEG_OFF     6656       // i32
#define CHUNKSTATE_OFF 6720       // NCHUNK * i32 = 32768
#define LG64_OFF       40960      // T*64 f64 = 33,554,432

// ---- d_out used as scratch before finalize overwrites it (deterministic)
#define CHUNKG_DOUT    0          // NCHUNK*64 u8 = 524288
#define SUPERS_DOUT    524288     // NSUPER*64 u8 = 8192
#define SUPSTATE_DOUT  532480     // NSUPER * i32 = 512

typedef unsigned long long ull;

// ---------------------------------------------------------------------------
// K1: adjacency bitmasks, padded neighbor lists (ascending, transposed),
//     base1/w1t precompute. Single block.
// ---------------------------------------------------------------------------
__global__ void prep_kernel(const float* __restrict__ pa,
                            const int* __restrict__ edges,
                            const float* __restrict__ W1,
                            const float* __restrict__ b1,
                            unsigned char* ws) {
  ull* adj = (ull*)(ws + ADJ_OFF);
  double* base1 = (double*)(ws + BASE1_OFF);
  double* w1t   = (double*)(ws + W1T_OFF);
  unsigned char* nbrT = ws + NBRT_OFF;
  __shared__ int smax;
  __shared__ int sdeg[NZ];
  int tid = threadIdx.x;
  if (tid == 0) smax = 0;
  if (tid < NZ) adj[tid] = 0ull;
  __syncthreads();
  if (tid < NEDGE) {
    int e0 = edges[tid];
    int e1 = edges[NEDGE + tid];
    atomicOr(&adj[e0], 1ull << e1);
    atomicOr(&adj[e1], 1ull << e0);
  }
  if (tid < NZ) atomicOr(&adj[tid], 1ull << tid);  // self loops
  if (tid < NH1) {
    double acc = (double)b1[tid];
    for (int d = 0; d < 64; ++d)
      acc += (double)pa[d] * (double)W1[d * NH1 + tid];
    base1[tid] = acc;
    w1t[tid] = (double)W1[64 * NH1 + tid];
  }
  __syncthreads();
  if (tid < NZ) {
    ull m = adj[tid];
    int deg = 0;
    while (m) {
      int j = __builtin_ctzll(m);
      m &= m - 1;
      nbrT[deg * 64 + tid] = (unsigned char)j;
      ++deg;
    }
    sdeg[tid] = deg;
    atomicMax(&smax, deg);
  }
  __syncthreads();
  if (tid < NZ) {
    int deg = sdeg[tid];
    unsigned char j0 = nbrT[0 * 64 + tid];  // deg >= 1 (self loop)
    for (int k = deg; k < smax; ++k) nbrT[k * 64 + tid] = j0;
  }
  if (tid == 0) *(int*)(ws + MAXDEG_OFF) = smax;
}

// ---------------------------------------------------------------------------
// K2: batched MLP -> f64 logits. One wave per 8 timesteps; 2 steps share each
// weight read; f64 accumulation throughout.
// ---------------------------------------------------------------------------
__global__ __launch_bounds__(256) void mlp_kernel(
    const float* __restrict__ times,
    const float* __restrict__ W2, const float* __restrict__ b2,
    const float* __restrict__ W3, const float* __restrict__ b3,
    const unsigned char* __restrict__ ws_ro,
    double* __restrict__ lg64) {
  __shared__ float W2s[NH1 * NH2];
  __shared__ float W3s[NH2 * NZ];
  __shared__ float b2s[NH2], b3s[NZ];
  __shared__ double base1s[NH1], w1ts[NH1];
  __shared__ double h1b[4][2][NH1];
  __shared__ double h2b[4][2][NH2];

  int tid = threadIdx.x;
  for (int i = tid; i < NH1 * NH2; i += 256) W2s[i] = W2[i];
  for (int i = tid; i < NH2 * NZ; i += 256) W3s[i] = W3[i];
  if (tid < NH2) b2s[tid] = b2[tid];
  if (tid < NZ)  b3s[tid] = b3[tid];
  if (tid < NH1) {
    base1s[tid] = ((const double*)(ws_ro + BASE1_OFF))[tid];
    w1ts[tid]   = ((const double*)(ws_ro + W1T_OFF))[tid];
  }
  __syncthreads();

  int lane = tid & 63, wv = tid >> 6;
  int wid = blockIdx.x * 4 + wv;
  size_t t0 = (size_t)wid * CL;
  for (int p = 0; p < CL / 2; ++p) {
    size_t t = t0 + p * 2;
    double tv0 = (double)times[t], tv1 = (double)times[t + 1];
    double a;
    a = base1s[lane] + tv0 * w1ts[lane];           h1b[wv][0][lane]      = a > 0.0 ? a : 0.0;
    a = base1s[lane + 64] + tv0 * w1ts[lane + 64]; h1b[wv][0][lane + 64] = a > 0.0 ? a : 0.0;
    a = base1s[lane] + tv1 * w1ts[lane];           h1b[wv][1][lane]      = a > 0.0 ? a : 0.0;
    a = base1s[lane + 64] + tv1 * w1ts[lane + 64]; h1b[wv][1][lane + 64] = a > 0.0 ? a : 0.0;
    __syncthreads();
    double acc0 = (double)b2s[lane], acc1 = acc0;
    double bcc0 = 0.0, bcc1 = 0.0;
    #pragma unroll 8
    for (int h = 0; h < NH1; h += 2) {
      double w0 = (double)W2s[h * NH2 + lane];
      double w1 = (double)W2s[(h + 1) * NH2 + lane];
      acc0 += h1b[wv][0][h] * w0;     acc1 += h1b[wv][1][h] * w0;
      bcc0 += h1b[wv][0][h + 1] * w1; bcc1 += h1b[wv][1][h + 1] * w1;
    }
    acc0 += bcc0; acc1 += bcc1;
    h2b[wv][0][lane] = acc0 > 0.0 ? acc0 : 0.0;
    h2b[wv][1][lane] = acc1 > 0.0 ? acc1 : 0.0;
    __syncthreads();
    double l0 = (double)b3s[lane], l1 = l0;
    double m0 = 0.0, m1 = 0.0;
    #pragma unroll 8
    for (int j = 0; j < NH2; j += 2) {
      double w0 = (double)W3s[j * NZ + lane];
      double w1 = (double)W3s[(j + 1) * NZ + lane];
      l0 += h2b[wv][0][j] * w0;     l1 += h2b[wv][1][j] * w0;
      m0 += h2b[wv][0][j + 1] * w1; m1 += h2b[wv][1][j + 1] * w1;
    }
    l0 += m0; l1 += m1;
    lg64[t * 64 + lane] = l0;
    lg64[(t + 1) * 64 + lane] = l1;
  }
}

// ---------------------------------------------------------------------------
// K3: per-chunk composed transition tables.
// F_t[z] = argmax_j(lg[j] - 1 + A[z][j]) computed as:
//   jmax = global argmax (butterfly); if A[z][jmax]: F=jmax
//   else compare best-neighbor v_n vs vmax-1 (exact f64, first-index ties)
// ---------------------------------------------------------------------------
__global__ __launch_bounds__(256) void chunk_tables_kernel(
    const double* __restrict__ lg64, const unsigned char* __restrict__ ws_ro,
    unsigned char* __restrict__ chunkG) {
  __shared__ double lgs[4][CL][64];
  __shared__ unsigned char nbrTs[4096];
  int tid = threadIdx.x, lane = tid & 63, wv = tid >> 6;
  for (int i = tid; i < 1024; i += 256)
    ((unsigned int*)nbrTs)[i] = ((const unsigned int*)(ws_ro + NBRT_OFF))[i];
  const int maxdeg = *(const int*)(ws_ro + MAXDEG_OFF);
  ull mask = ((const ull*)(ws_ro + ADJ_OFF))[lane];
  int c = blockIdx.x * 4 + wv;
  size_t tb = (size_t)c * CL * 64;
  double lg[CL];
  #pragma unroll
  for (int i = 0; i < CL; ++i) lg[i] = lg64[tb + i * 64 + lane];
  #pragma unroll
  for (int i = 0; i < CL; ++i) lgs[wv][i][lane] = lg[i];
  __syncthreads();

  // best neighbor per step (shared k loop: neighbor list is step-invariant)
  double vn[CL];
  int jn[CL];
  #pragma unroll
  for (int i = 0; i < CL; ++i) { vn[i] = -1.0e300; jn[i] = 0; }
  #pragma unroll 2
  for (int k = 0; k < maxdeg; ++k) {
    int j = nbrTs[k * 64 + lane];
    #pragma unroll
    for (int i = 0; i < CL; ++i) {
      double val = lgs[wv][i][j];
      if (val > vn[i]) { vn[i] = val; jn[i] = j; }  // ascending j, strict >
    }
  }

  int F[CL];
  #pragma unroll
  for (int i = 0; i < CL; ++i) {
    double v = lg[i];
    int idx = lane;
    #pragma unroll
    for (int off = 1; off < 64; off <<= 1) {
      double ov = __shfl_xor(v, off, 64);
      int oi = __shfl_xor(idx, off, 64);
      if (ov > v || (ov == v && oi < idx)) { v = ov; idx = oi; }
    }
    int f;
    if ((mask >> idx) & 1ull) f = idx;
    else {
      double vg = v - 1.0;
      if (vn[i] > vg) f = jn[i];
      else if (vn[i] < vg) f = idx;
      else f = jn[i] < idx ? jn[i] : idx;
    }
    F[i] = f;
  }
  int cur = lane;
  #pragma unroll
  for (int i = 0; i < CL; ++i) cur = __shfl(F[i], cur, 64);
  chunkG[(size_t)c * 64 + lane] = (unsigned char)cur;
}

// ---------------------------------------------------------------------------
// K4: compose SUP_L chunk tables into each super table (NSUPER waves)
// ---------------------------------------------------------------------------
__global__ void super_compose_kernel(const unsigned char* __restrict__ chunkG,
                                     unsigned char* __restrict__ superS) {
  int lane = threadIdx.x & 63, wv = threadIdx.x >> 6;
  int k = blockIdx.x * 4 + wv;
  int cur = lane;
  #pragma unroll 8
  for (int c = k * SUP_L; c < (k + 1) * SUP_L; ++c) {
    int g = chunkG[(size_t)c * 64 + lane];
    cur = __shfl(g, cur, 64);
  }
  superS[(size_t)k * 64 + lane] = (unsigned char)cur;
}

// ---------------------------------------------------------------------------
// K5: sequential walk over NSUPER super tables (1 wave, tables in LDS)
// ---------------------------------------------------------------------------
__global__ void super_walk_kernel(const unsigned char* __restrict__ superS,
                                  int* __restrict__ supState) {
  __shared__ unsigned char ssup[NSUPER * 64];
  int lane = threadIdx.x;
  for (int i = lane; i < NSUPER * 16; i += 64)
    ((unsigned int*)ssup)[i] = ((const unsigned int*)superS)[i];
  __syncthreads();
  int s = 0;
  if (lane == 0) supState[0] = 0;
  for (int k = 0; k < NSUPER; ++k) {
    int v = ssup[k * 64 + lane];
    s = __shfl(v, s, 64);
    if (lane == 0 && k + 1 < NSUPER) supState[k + 1] = s;
  }
}

// ---------------------------------------------------------------------------
// K6: per-chunk start states within each super (NSUPER waves)
// ---------------------------------------------------------------------------
__global__ void chunk_states_kernel(const unsigned char* __restrict__ chunkG,
                                    const int* __restrict__ supState,
                                    int* __restrict__ chunkState) {
  int lane = threadIdx.x & 63, wv = threadIdx.x >> 6;
  int k = blockIdx.x * 4 + wv;
  int s = supState[k];
  #pragma unroll 8
  for (int c = k * SUP_L; c < (k + 1) * SUP_L; ++c) {
    if (lane == 0) chunkState[c] = s;
    int g = chunkG[(size_t)c * 64 + lane];
    s = __shfl(g, s, 64);
  }
}

// ---------------------------------------------------------------------------
// K7: finalize — walk each 8-step chunk from its entry state, write
// out = (float)(logits - 1 + A[z_t]) from f64 logits.
// ---------------------------------------------------------------------------
__global__ __launch_bounds__(256) void finalize_kernel(
    const double* __restrict__ lg64, const unsigned char* __restrict__ ws_ro,
    const int* __restrict__ chunkState, float* __restrict__ out) {
  __shared__ ull adjs[64];
  int tid = threadIdx.x, lane = tid & 63, wv = tid >> 6;
  if (tid < 64) adjs[tid] = ((const ull*)(ws_ro + ADJ_OFF))[tid];
  __syncthreads();
  int c = blockIdx.x * 4 + wv;
  int s = chunkState[c];
  size_t tb = (size_t)c * CL * 64;
  #pragma unroll
  for (int i = 0; i < CL; ++i) {
    double lg = lg64[tb + i * 64 + lane];
    int bit = (int)((adjs[s] >> lane) & 1ull);
    double v = bit ? lg : lg - 1.0;
    out[tb + i * 64 + lane] = (float)v;
    int idx = lane;
    #pragma unroll
    for (int off = 1; off < 64; off <<= 1) {
      double ov = __shfl_xor(v, off, 64);
      int oi = __shfl_xor(idx, off, 64);
      if (ov > v || (ov == v && oi < idx)) { v = ov; idx = oi; }
    }
    s = idx;  // uniform across lanes
  }
}

// ---------------------------------------------------------------------------
extern "C" void kernel_launch(void* const* d_in, const int* in_sizes, int n_in,
                              void* d_out, int out_size, void* d_ws, size_t ws_size,
                              hipStream_t stream) {
  const float* pa    = (const float*)d_in[0];
  const float* times = (const float*)d_in[1];
  // d_in[2] zone_features: unused by the reference
  const int*   edges = (const int*)d_in[3];
  const float* W1    = (const float*)d_in[4];
  const float* b1    = (const float*)d_in[5];
  const float* W2    = (const float*)d_in[6];
  const float* b2    = (const float*)d_in[7];
  const float* W3    = (const float*)d_in[8];
  const float* b3    = (const float*)d_in[9];

  unsigned char* ws = (unsigned char*)d_ws;
  unsigned char* outb = (unsigned char*)d_out;  // scratch until finalize
  double* lg64 = (double*)(ws + LG64_OFF);
  unsigned char* chunkG = outb + CHUNKG_DOUT;
  unsigned char* superS = outb + SUPERS_DOUT;
  int* supState = (int*)(outb + SUPSTATE_DOUT);
  int* chunkState = (int*)(ws + CHUNKSTATE_OFF);

  hipLaunchKernelGGL(prep_kernel, dim3(1), dim3(512), 0, stream, pa, edges, W1, b1, ws);
  hipLaunchKernelGGL(mlp_kernel, dim3(T_STEPS / CL / 4), dim3(256), 0, stream,
                     times, W2, b2, W3, b3, ws, lg64);
  hipLaunchKernelGGL(chunk_tables_kernel, dim3(NCHUNK / 4), dim3(256), 0, stream,
                     lg64, ws, chunkG);
  hipLaunchKernelGGL(super_compose_kernel, dim3(NSUPER / 4), dim3(256), 0, stream,
                     chunkG, superS);
  hipLaunchKernelGGL(super_walk_kernel, dim3(1), dim3(64), 0, stream,
                     superS, supState);
  hipLaunchKernelGGL(chunk_states_kernel, dim3(NSUPER / 4), dim3(256), 0, stream,
                     chunkG, supState, chunkState);
  hipLaunchKernelGGL(finalize_kernel, dim3(NCHUNK / 4), dim3(256), 0, stream,
                     lg64, ws, chunkState, (float*)d_out);
}